// Round 1
// baseline (4614.592 us; speedup 1.0000x reference)
//
#include <hip/hip_runtime.h>

// Problem constants (match reference setup_inputs)
#define E_  200000
#define U_  50000
#define D_  128
#define R_  32
#define N2_ 100000
#define N1_ 80000
#define NU_ 20000
#define M1_ 1600000
#define M0_ 800000

__device__ __forceinline__ float4 ld4(const float* p) {
    return *reinterpret_cast<const float4*>(p);
}
__device__ __forceinline__ void st4(float* p, float4 v) {
    *reinterpret_cast<float4*>(p) = v;
}

__device__ __forceinline__ float fast_tanh(float x) {
    // tanh(x) = 1 - 2/(exp(2x)+1); exact limits at +-inf
    float e = __expf(2.0f * x);
    return 1.0f - 2.0f / (e + 1.0f);
}

// out[i][:] = src[idx[i]][:]   (one float4 per thread, 32 threads/row)
__global__ __launch_bounds__(256) void gather_rows_k(
    const float* __restrict__ src, const int* __restrict__ idx,
    float* __restrict__ out, int n)
{
    long long gid = (long long)blockIdx.x * blockDim.x + threadIdx.x;
    int i = (int)(gid >> 5);
    int l = (int)(gid & 31);
    if (i >= n) return;
    int s = idx[i];
    st4(out + (long long)i * 128 + l * 4, ld4(src + (long long)s * 128 + l * 4));
}

// per edge: agg[dst] += tail[src] * rel_emb[rel];  deg[dst] += 1
// 32 threads per edge, 4 floats each.
__global__ __launch_bounds__(256) void edge_scatter_k(
    const float* __restrict__ tail, const float* __restrict__ rel_emb,
    const int* __restrict__ src, const int* __restrict__ dst,
    const int* __restrict__ rel,
    float* __restrict__ agg, float* __restrict__ deg, int M)
{
    long long gid = (long long)blockIdx.x * blockDim.x + threadIdx.x;
    int e = (int)(gid >> 5);
    int l = (int)(gid & 31);
    if (e >= M) return;
    int s = src[e], d = dst[e], r = rel[e];
    float4 t  = ld4(tail    + (long long)s * 128 + l * 4);
    float4 rm = ld4(rel_emb + (long long)r * 128 + l * 4);
    float* a = agg + (long long)d * 128 + l * 4;
    atomicAdd(a + 0, t.x * rm.x);
    atomicAdd(a + 1, t.y * rm.y);
    atomicAdd(a + 2, t.z * rm.z);
    atomicAdd(a + 3, t.w * rm.w);
    if (l == 0) atomicAdd(deg + d, 1.0f);
}

// Out[rowbase+r][:] (op)= act( Xrow @ W (+ bias) )
// Xrow = X[idx[row]] (GATHER) or X[row]; scaled by 1/max(deg[row],1) (DIVDEG).
// ACCUM: Out += result (reads previous Out). ACT: tanh at the end.
// Tile: 128 rows x 128 cols per block, 256 threads, 8x8 per thread.
// K staged in 4 chunks of 32. X staged transposed with XOR swizzle so the
// inner loop is pure ds_read_b128 on both operands.
template<bool GATHER, bool DIVDEG, bool ACCUM, bool BIAS, bool ACT>
__global__ __launch_bounds__(256) void gemm_rows_k(
    const float* __restrict__ X, const int* __restrict__ idx,
    const float* __restrict__ deg, const float* __restrict__ W,
    const float* __restrict__ bias, float* __restrict__ Out, int N)
{
    __shared__ float XsT[32][128];  // [k][row ^ swz(k)]
    __shared__ float Ws [32][128];  // [k][c]
    const int tid = threadIdx.x;
    const int rowbase = blockIdx.x * 128;
    const int rg = tid >> 4;        // 0..15
    const int cg = tid & 15;        // 0..15
    const int r0 = rg * 8;
    const int c0 = cg * 8;

    float acc[8][8];
    if (BIAS) {
        #pragma unroll
        for (int j = 0; j < 8; ++j) {
            float bv = bias[c0 + j];
            #pragma unroll
            for (int i = 0; i < 8; ++i) acc[i][j] = bv;
        }
    } else {
        #pragma unroll
        for (int i = 0; i < 8; ++i)
            #pragma unroll
            for (int j = 0; j < 8; ++j) acc[i][j] = 0.0f;
    }

    const int srow = tid >> 3;         // 0..31 (row group for X staging)
    const int skq  = (tid & 7) * 4;    // k offset within chunk
    const int sswz = (tid & 7) << 2;   // swizzle for those 4 k's
    const int wkk  = tid >> 5;         // 0..7  (k group for W staging)
    const int wcc  = (tid & 31) * 4;   // col offset for W staging

    for (int k0 = 0; k0 < 128; k0 += 32) {
        __syncthreads();
        // stage X transposed: rows 0..127 (4 passes of 32), k chunk of 32
        #pragma unroll
        for (int p = 0; p < 4; ++p) {
            int row = p * 32 + srow;
            int grow = rowbase + row;
            int cl = grow < N ? grow : (N - 1);
            const float* xr;
            if (GATHER) xr = X + (long long)idx[cl] * 128;
            else        xr = X + (long long)cl * 128;
            float4 v = ld4(xr + k0 + skq);
            if (DIVDEG) {
                float sc = 1.0f / fmaxf(deg[cl], 1.0f);
                v.x *= sc; v.y *= sc; v.z *= sc; v.w *= sc;
            }
            int rs = row ^ sswz;
            XsT[skq + 0][rs] = v.x;
            XsT[skq + 1][rs] = v.y;
            XsT[skq + 2][rs] = v.z;
            XsT[skq + 3][rs] = v.w;
        }
        // stage W chunk [32 k][128 c]
        #pragma unroll
        for (int p = 0; p < 4; ++p) {
            int k = p * 8 + wkk;
            st4(&Ws[k][wcc], ld4(W + (long long)(k0 + k) * 128 + wcc));
        }
        __syncthreads();
        // compute 32 k-steps
        #pragma unroll
        for (int k = 0; k < 32; ++k) {
            int A0 = (((r0 >> 2) ^ ((k >> 2) & 7)) << 2);
            float4 x0 = ld4(&XsT[k][A0]);
            float4 x1 = ld4(&XsT[k][A0 ^ 4]);
            float4 w0 = ld4(&Ws[k][c0]);
            float4 w1 = ld4(&Ws[k][c0 + 4]);
            float xs[8] = {x0.x, x0.y, x0.z, x0.w, x1.x, x1.y, x1.z, x1.w};
            float ws[8] = {w0.x, w0.y, w0.z, w0.w, w1.x, w1.y, w1.z, w1.w};
            #pragma unroll
            for (int i = 0; i < 8; ++i)
                #pragma unroll
                for (int j = 0; j < 8; ++j)
                    acc[i][j] = fmaf(xs[i], ws[j], acc[i][j]);
        }
    }

    // epilogue
    #pragma unroll
    for (int i = 0; i < 8; ++i) {
        int row = rowbase + r0 + i;
        if (row >= N) continue;
        float* op = Out + (long long)row * 128 + c0;
        float vals[8];
        #pragma unroll
        for (int j = 0; j < 8; ++j) vals[j] = acc[i][j];
        if (ACCUM) {
            float4 o0 = ld4(op), o1 = ld4(op + 4);
            vals[0] += o0.x; vals[1] += o0.y; vals[2] += o0.z; vals[3] += o0.w;
            vals[4] += o1.x; vals[5] += o1.y; vals[6] += o1.z; vals[7] += o1.w;
        }
        if (ACT) {
            #pragma unroll
            for (int j = 0; j < 8; ++j) vals[j] = fast_tanh(vals[j]);
        }
        st4(op,     make_float4(vals[0], vals[1], vals[2], vals[3]));
        st4(op + 4, make_float4(vals[4], vals[5], vals[6], vals[7]));
    }
}

extern "C" void kernel_launch(void* const* d_in, const int* in_sizes, int n_in,
                              void* d_out, int out_size, void* d_ws, size_t ws_size,
                              hipStream_t stream)
{
    const float* ent_emb  = (const float*)d_in[0];
    const float* user_emb = (const float*)d_in[1];
    const float* rel_emb  = (const float*)d_in[2];
    const float* W_self   = (const float*)d_in[3];
    const float* W_nei    = (const float*)d_in[4];
    const float* bvec     = (const float*)d_in[5];
    const int* final_indices = (const int*)d_in[6];
    const int* ent_now1   = (const int*)d_in[7];
    const int* e1_src     = (const int*)d_in[8];
    const int* e1_dst     = (const int*)d_in[9];
    const int* e1_rel     = (const int*)d_in[10];
    const int* e0_src     = (const int*)d_in[11];
    const int* e0_dst     = (const int*)d_in[12];
    const int* e0_rel     = (const int*)d_in[13];
    const int* unreach_idx = (const int*)d_in[14];
    const int* order      = (const int*)d_in[15];

    float* out = (float*)d_out;
    float* ws  = (float*)d_ws;

    // ws layout (floats):
    // concat_buf[E*128] = [h1 (N1) | h2 (N2) | unreach (NU)] rows
    // agg1[N1*128], deg1[N1], agg0[U*128], deg0[U]  (contiguous for one memset)
    float* concat = ws;
    float* agg1 = concat + (size_t)E_ * 128;
    float* deg1 = agg1 + (size_t)N1_ * 128;
    float* agg0 = deg1 + N1_;
    float* deg0 = agg0 + (size_t)U_ * 128;
    float* h1   = concat;                             // rows [0, N1)
    float* h2   = concat + (size_t)N1_ * 128;         // rows [N1, N1+N2)
    float* unre = concat + (size_t)(N1_ + N2_) * 128; // rows [N1+N2, E)

    // zero all accumulators + degrees in one memset (they are contiguous)
    size_t zbytes = ((size_t)N1_ * 128 + N1_ + (size_t)U_ * 128 + U_) * sizeof(float);
    hipMemsetAsync(agg1, 0, zbytes, stream);

    // h2 = ent_emb[final_indices]
    {
        long long th = (long long)N2_ * 32;
        gather_rows_k<<<(int)((th + 255) / 256), 256, 0, stream>>>(
            ent_emb, final_indices, h2, N2_);
    }
    // layer-1 aggregation: agg1[dst] += h2[src]*rel_emb[rel], deg1[dst]++
    {
        long long th = (long long)M1_ * 32;
        edge_scatter_k<<<(int)((th + 255) / 256), 256, 0, stream>>>(
            h2, rel_emb, e1_src, e1_dst, e1_rel, agg1, deg1, M1_);
    }
    // h1 = tanh( ent_emb[ent_now1]@W_self + b + (agg1/deg1)@W_nei )
    gemm_rows_k<true,  false, false, true,  false><<<(N1_ + 127) / 128, 256, 0, stream>>>(
        ent_emb, ent_now1, nullptr, W_self, bvec, h1, N1_);
    gemm_rows_k<false, true,  true,  false, true ><<<(N1_ + 127) / 128, 256, 0, stream>>>(
        agg1, nullptr, deg1, W_nei, nullptr, h1, N1_);
    // layer-0 aggregation: agg0[dst] += h1[src]*rel_emb[rel], deg0[dst]++
    {
        long long th = (long long)M0_ * 32;
        edge_scatter_k<<<(int)((th + 255) / 256), 256, 0, stream>>>(
            h1, rel_emb, e0_src, e0_dst, e0_rel, agg0, deg0, M0_);
    }
    // user_rep = user_emb@W_self + b + (agg0/deg0)@W_nei   (no tanh)
    gemm_rows_k<false, false, false, true,  false><<<(U_ + 127) / 128, 256, 0, stream>>>(
        user_emb, nullptr, nullptr, W_self, bvec, out, U_);
    gemm_rows_k<false, true,  true,  false, false><<<(U_ + 127) / 128, 256, 0, stream>>>(
        agg0, nullptr, deg0, W_nei, nullptr, out, U_);
    // unreachable = tanh( ent_emb[unreach_idx]@W_self + b )
    gemm_rows_k<true,  false, false, true,  true ><<<(NU_ + 127) / 128, 256, 0, stream>>>(
        ent_emb, unreach_idx, nullptr, W_self, bvec, unre, NU_);
    // final reorder: out[U + i] = concat[order[i]]
    {
        long long th = (long long)E_ * 32;
        gather_rows_k<<<(int)((th + 255) / 256), 256, 0, stream>>>(
            concat, order, out + (size_t)U_ * 128, E_);
    }
}

// Round 2
// 1136.296 us; speedup vs baseline: 4.0611x; 4.0611x over previous
//
#include <hip/hip_runtime.h>

// Problem constants (match reference setup_inputs)
#define E_  200000
#define U_  50000
#define D_  128
#define R_  32
#define N2_ 100000
#define N1_ 80000
#define NU_ 20000
#define M1_ 1600000
#define M0_ 800000

__device__ __forceinline__ float4 ld4(const float* p) {
    return *reinterpret_cast<const float4*>(p);
}
__device__ __forceinline__ void st4(float* p, float4 v) {
    *reinterpret_cast<float4*>(p) = v;
}

__device__ __forceinline__ float fast_tanh(float x) {
    float e = __expf(2.0f * x);
    return 1.0f - 2.0f / (e + 1.0f);
}

// ---------------------------------------------------------------------------
// out[i][:] = src[idx[i]][:]   (one float4 per thread, 32 threads/row)
__global__ __launch_bounds__(256) void gather_rows_k(
    const float* __restrict__ src, const int* __restrict__ idx,
    float* __restrict__ out, int n)
{
    long long gid = (long long)blockIdx.x * blockDim.x + threadIdx.x;
    int i = (int)(gid >> 5);
    int l = (int)(gid & 31);
    if (i >= n) return;
    int s = idx[i];
    st4(out + (long long)i * 128 + l * 4, ld4(src + (long long)s * 128 + l * 4));
}

// ---------------------------------------------------------------------------
// CSR build: histogram -> exclusive scan -> cursor scatter of packed edges
__global__ __launch_bounds__(256) void hist_k(
    const int* __restrict__ dst, int* __restrict__ cnt, int M)
{
    int i = blockIdx.x * blockDim.x + threadIdx.x;
    if (i < M) atomicAdd(&cnt[dst[i]], 1);
}

// Single-block exclusive scan over N counts (N <= 1024*chunk).
// Reads counts from `cur`, writes off[0..N] and resets cur[i]=off[i] (cursor).
__global__ __launch_bounds__(1024) void scan_k(
    int* __restrict__ cur, int* __restrict__ off, int N)
{
    __shared__ int ls[1024];
    const int t = threadIdx.x;
    const int chunk = (N + 1023) >> 10;
    const int s = t * chunk;
    const int e = min(s + chunk, N);
    int sum = 0;
    for (int i = s; i < e; ++i) sum += cur[i];
    ls[t] = sum;
    __syncthreads();
    #pragma unroll
    for (int d = 1; d < 1024; d <<= 1) {
        int v = (t >= d) ? ls[t - d] : 0;
        __syncthreads();
        ls[t] += v;
        __syncthreads();
    }
    int run = (t == 0) ? 0 : ls[t - 1];
    for (int i = s; i < e; ++i) {
        int c = cur[i];
        off[i] = run;
        cur[i] = run;
        run += c;
    }
    if (t == 1023) off[N] = ls[1023];
}

// sorted[pos] = src | (rel << 20), pos = cur[dst]++
__global__ __launch_bounds__(256) void fill_k(
    const int* __restrict__ src, const int* __restrict__ dst,
    const int* __restrict__ rel, int* __restrict__ cur,
    int* __restrict__ sorted, int M)
{
    int i = blockIdx.x * blockDim.x + threadIdx.x;
    if (i >= M) return;
    int p = atomicAdd(&cur[dst[i]], 1);
    sorted[p] = src[i] | (rel[i] << 20);
}

// ---------------------------------------------------------------------------
// Per-dst mean aggregation: 32 lanes own one row, iterate its CSR segment.
// aggout[row] = (1/max(deg,1)) * sum_j tail[src_j] * rel_emb[rel_j]
__global__ __launch_bounds__(256) void seg_reduce_k(
    const float* __restrict__ tail, const float* __restrict__ rel_emb,
    const int* __restrict__ off, const int* __restrict__ sorted,
    float* __restrict__ aggout, int N)
{
    long long gid = (long long)blockIdx.x * blockDim.x + threadIdx.x;
    int row = (int)(gid >> 5);
    int l = (int)(gid & 31) * 4;
    if (row >= N) return;
    int s = off[row], e = off[row + 1];
    float4 acc = make_float4(0.f, 0.f, 0.f, 0.f);
    int j = s;
    for (; j + 1 < e; j += 2) {
        int p0 = sorted[j], p1 = sorted[j + 1];
        float4 t0 = ld4(tail + (long long)(p0 & 0xFFFFF) * 128 + l);
        float4 r0 = ld4(rel_emb + (long long)(p0 >> 20) * 128 + l);
        float4 t1 = ld4(tail + (long long)(p1 & 0xFFFFF) * 128 + l);
        float4 r1 = ld4(rel_emb + (long long)(p1 >> 20) * 128 + l);
        acc.x = fmaf(t0.x, r0.x, acc.x); acc.y = fmaf(t0.y, r0.y, acc.y);
        acc.z = fmaf(t0.z, r0.z, acc.z); acc.w = fmaf(t0.w, r0.w, acc.w);
        acc.x = fmaf(t1.x, r1.x, acc.x); acc.y = fmaf(t1.y, r1.y, acc.y);
        acc.z = fmaf(t1.z, r1.z, acc.z); acc.w = fmaf(t1.w, r1.w, acc.w);
    }
    if (j < e) {
        int p0 = sorted[j];
        float4 t0 = ld4(tail + (long long)(p0 & 0xFFFFF) * 128 + l);
        float4 r0 = ld4(rel_emb + (long long)(p0 >> 20) * 128 + l);
        acc.x = fmaf(t0.x, r0.x, acc.x); acc.y = fmaf(t0.y, r0.y, acc.y);
        acc.z = fmaf(t0.z, r0.z, acc.z); acc.w = fmaf(t0.w, r0.w, acc.w);
    }
    float sc = 1.0f / (float)max(e - s, 1);
    acc.x *= sc; acc.y *= sc; acc.z *= sc; acc.w *= sc;
    st4(aggout + (long long)row * 128 + l, acc);
}

// ---------------------------------------------------------------------------
// Out[rowbase+r][:] (op)= act( Xrow @ W (+ bias) )
// Tile: 128 rows x 128 cols per block, 256 threads, 8x8 per thread.
template<bool GATHER, bool ACCUM, bool BIAS, bool ACT>
__global__ __launch_bounds__(256) void gemm_rows_k(
    const float* __restrict__ X, const int* __restrict__ idx,
    const float* __restrict__ W, const float* __restrict__ bias,
    float* __restrict__ Out, int N)
{
    __shared__ float XsT[32][128];  // [k][row ^ swz(k)]
    __shared__ float Ws [32][128];  // [k][c]
    const int tid = threadIdx.x;
    const int rowbase = blockIdx.x * 128;
    const int rg = tid >> 4;
    const int cg = tid & 15;
    const int r0 = rg * 8;
    const int c0 = cg * 8;

    float acc[8][8];
    if (BIAS) {
        #pragma unroll
        for (int j = 0; j < 8; ++j) {
            float bv = bias[c0 + j];
            #pragma unroll
            for (int i = 0; i < 8; ++i) acc[i][j] = bv;
        }
    } else {
        #pragma unroll
        for (int i = 0; i < 8; ++i)
            #pragma unroll
            for (int j = 0; j < 8; ++j) acc[i][j] = 0.0f;
    }

    const int srow = tid >> 3;
    const int skq  = (tid & 7) * 4;
    const int sswz = (tid & 7) << 2;
    const int wkk  = tid >> 5;
    const int wcc  = (tid & 31) * 4;

    for (int k0 = 0; k0 < 128; k0 += 32) {
        __syncthreads();
        #pragma unroll
        for (int p = 0; p < 4; ++p) {
            int row = p * 32 + srow;
            int grow = rowbase + row;
            int cl = grow < N ? grow : (N - 1);
            const float* xr;
            if (GATHER) xr = X + (long long)idx[cl] * 128;
            else        xr = X + (long long)cl * 128;
            float4 v = ld4(xr + k0 + skq);
            int rs = row ^ sswz;
            XsT[skq + 0][rs] = v.x;
            XsT[skq + 1][rs] = v.y;
            XsT[skq + 2][rs] = v.z;
            XsT[skq + 3][rs] = v.w;
        }
        #pragma unroll
        for (int p = 0; p < 4; ++p) {
            int k = p * 8 + wkk;
            st4(&Ws[k][wcc], ld4(W + (long long)(k0 + k) * 128 + wcc));
        }
        __syncthreads();
        #pragma unroll
        for (int k = 0; k < 32; ++k) {
            int A0 = (((r0 >> 2) ^ ((k >> 2) & 7)) << 2);
            float4 x0 = ld4(&XsT[k][A0]);
            float4 x1 = ld4(&XsT[k][A0 ^ 4]);
            float4 w0 = ld4(&Ws[k][c0]);
            float4 w1 = ld4(&Ws[k][c0 + 4]);
            float xs[8] = {x0.x, x0.y, x0.z, x0.w, x1.x, x1.y, x1.z, x1.w};
            float ws[8] = {w0.x, w0.y, w0.z, w0.w, w1.x, w1.y, w1.z, w1.w};
            #pragma unroll
            for (int i = 0; i < 8; ++i)
                #pragma unroll
                for (int j = 0; j < 8; ++j)
                    acc[i][j] = fmaf(xs[i], ws[j], acc[i][j]);
        }
    }

    #pragma unroll
    for (int i = 0; i < 8; ++i) {
        int row = rowbase + r0 + i;
        if (row >= N) continue;
        float* op = Out + (long long)row * 128 + c0;
        float vals[8];
        #pragma unroll
        for (int j = 0; j < 8; ++j) vals[j] = acc[i][j];
        if (ACCUM) {
            float4 o0 = ld4(op), o1 = ld4(op + 4);
            vals[0] += o0.x; vals[1] += o0.y; vals[2] += o0.z; vals[3] += o0.w;
            vals[4] += o1.x; vals[5] += o1.y; vals[6] += o1.z; vals[7] += o1.w;
        }
        if (ACT) {
            #pragma unroll
            for (int j = 0; j < 8; ++j) vals[j] = fast_tanh(vals[j]);
        }
        st4(op,     make_float4(vals[0], vals[1], vals[2], vals[3]));
        st4(op + 4, make_float4(vals[4], vals[5], vals[6], vals[7]));
    }
}

// ---------------------------------------------------------------------------
extern "C" void kernel_launch(void* const* d_in, const int* in_sizes, int n_in,
                              void* d_out, int out_size, void* d_ws, size_t ws_size,
                              hipStream_t stream)
{
    const float* ent_emb  = (const float*)d_in[0];
    const float* user_emb = (const float*)d_in[1];
    const float* rel_emb  = (const float*)d_in[2];
    const float* W_self   = (const float*)d_in[3];
    const float* W_nei    = (const float*)d_in[4];
    const float* bvec     = (const float*)d_in[5];
    const int* final_indices = (const int*)d_in[6];
    const int* ent_now1   = (const int*)d_in[7];
    const int* e1_src     = (const int*)d_in[8];
    const int* e1_dst     = (const int*)d_in[9];
    const int* e1_rel     = (const int*)d_in[10];
    const int* e0_src     = (const int*)d_in[11];
    const int* e0_dst     = (const int*)d_in[12];
    const int* e0_rel     = (const int*)d_in[13];
    const int* unreach_idx = (const int*)d_in[14];
    const int* order      = (const int*)d_in[15];

    float* out = (float*)d_out;
    float* ws  = (float*)d_ws;

    // ws layout:
    // concat[E*128] = [h1 (N1) | h2 (N2) | unreach (NU)] rows
    // agg1[N1*128], agg0[U*128]
    // ints: cur1[N1], cur0[U] (contiguous, one memset), off1[N1+1], off0[U+1],
    //       sorted1[M1], sorted0[M0]
    float* concat = ws;
    float* agg1 = concat + (size_t)E_ * 128;
    float* agg0 = agg1 + (size_t)N1_ * 128;
    int* cur1 = (int*)(agg0 + (size_t)U_ * 128);
    int* cur0 = cur1 + N1_;
    int* off1 = cur0 + U_;
    int* off0 = off1 + (N1_ + 1);
    int* sorted1 = off0 + (U_ + 1);
    int* sorted0 = sorted1 + M1_;

    float* h1   = concat;
    float* h2   = concat + (size_t)N1_ * 128;
    float* unre = concat + (size_t)(N1_ + N2_) * 128;

    // zero histogram counters (cur1|cur0 contiguous)
    hipMemsetAsync(cur1, 0, (size_t)(N1_ + U_) * sizeof(int), stream);

    // h2 = ent_emb[final_indices]
    gather_rows_k<<<(N2_ * 32 + 255) / 256, 256, 0, stream>>>(
        ent_emb, final_indices, h2, N2_);

    // --- layer-1 CSR build + mean-aggregate into agg1 ---
    hist_k<<<(M1_ + 255) / 256, 256, 0, stream>>>(e1_dst, cur1, M1_);
    scan_k<<<1, 1024, 0, stream>>>(cur1, off1, N1_);
    fill_k<<<(M1_ + 255) / 256, 256, 0, stream>>>(
        e1_src, e1_dst, e1_rel, cur1, sorted1, M1_);
    seg_reduce_k<<<(N1_ * 32 + 255) / 256, 256, 0, stream>>>(
        h2, rel_emb, off1, sorted1, agg1, N1_);

    // h1 = tanh( ent_emb[ent_now1]@W_self + b + agg1@W_nei )
    gemm_rows_k<true,  false, true,  false><<<(N1_ + 127) / 128, 256, 0, stream>>>(
        ent_emb, ent_now1, W_self, bvec, h1, N1_);
    gemm_rows_k<false, true,  false, true ><<<(N1_ + 127) / 128, 256, 0, stream>>>(
        agg1, nullptr, W_nei, nullptr, h1, N1_);

    // --- layer-0 CSR build + mean-aggregate into agg0 ---
    hist_k<<<(M0_ + 255) / 256, 256, 0, stream>>>(e0_dst, cur0, M0_);
    scan_k<<<1, 1024, 0, stream>>>(cur0, off0, U_);
    fill_k<<<(M0_ + 255) / 256, 256, 0, stream>>>(
        e0_src, e0_dst, e0_rel, cur0, sorted0, M0_);
    seg_reduce_k<<<(U_ * 32 + 255) / 256, 256, 0, stream>>>(
        h1, rel_emb, off0, sorted0, agg0, U_);

    // user_rep = user_emb@W_self + b + agg0@W_nei   (no tanh)
    gemm_rows_k<false, false, true,  false><<<(U_ + 127) / 128, 256, 0, stream>>>(
        user_emb, nullptr, W_self, bvec, out, U_);
    gemm_rows_k<false, true,  false, false><<<(U_ + 127) / 128, 256, 0, stream>>>(
        agg0, nullptr, W_nei, nullptr, out, U_);

    // unreachable = tanh( ent_emb[unreach_idx]@W_self + b )
    gemm_rows_k<true,  false, true,  true ><<<(NU_ + 127) / 128, 256, 0, stream>>>(
        ent_emb, unreach_idx, W_self, bvec, unre, NU_);

    // final reorder: out[U + i] = concat[order[i]]
    gather_rows_k<<<(E_ * 32 + 255) / 256, 256, 0, stream>>>(
        concat, order, out + (size_t)U_ * 128, E_);
}

// Round 3
// 912.220 us; speedup vs baseline: 5.0586x; 1.2456x over previous
//
#include <hip/hip_runtime.h>

// Problem constants (match reference setup_inputs)
#define E_  200000
#define U_  50000
#define D_  128
#define R_  32
#define N2_ 100000
#define N1_ 80000
#define NU_ 20000
#define M1_ 1600000
#define M0_ 800000

__device__ __forceinline__ float4 ld4(const float* p) {
    return *reinterpret_cast<const float4*>(p);
}
__device__ __forceinline__ void st4(float* p, float4 v) {
    *reinterpret_cast<float4*>(p) = v;
}

__device__ __forceinline__ float fast_tanh(float x) {
    float e = __expf(2.0f * x);
    return 1.0f - 2.0f / (e + 1.0f);
}

// ---------------------------------------------------------------------------
// out[i][:] = src[idx[i]][:]   (one float4 per thread, 32 threads/row)
__global__ __launch_bounds__(256) void gather_rows_k(
    const float* __restrict__ src, const int* __restrict__ idx,
    float* __restrict__ out, int n)
{
    long long gid = (long long)blockIdx.x * blockDim.x + threadIdx.x;
    int i = (int)(gid >> 5);
    int l = (int)(gid & 31);
    if (i >= n) return;
    int s = idx[i];
    st4(out + (long long)i * 128 + l * 4, ld4(src + (long long)s * 128 + l * 4));
}

// ---------------------------------------------------------------------------
// CSR build: histogram -> hierarchical exclusive scan -> cursor scatter
__global__ __launch_bounds__(256) void hist_k(
    const int* __restrict__ dst, int* __restrict__ cnt, int M)
{
    int i = blockIdx.x * blockDim.x + threadIdx.x;
    if (i < M) atomicAdd(&cnt[dst[i]], 1);
}

// Phase 1: per-1024-element block sums (coalesced strided reads)
__global__ __launch_bounds__(256) void partial_sums_k(
    const int* __restrict__ cnt, int* __restrict__ bsum, int N)
{
    __shared__ int sm[256];
    const int t = threadIdx.x;
    const int base = blockIdx.x * 1024;
    int sum = 0;
    #pragma unroll
    for (int i = 0; i < 4; ++i) {
        int g = base + t + i * 256;
        if (g < N) sum += cnt[g];
    }
    sm[t] = sum;
    __syncthreads();
    #pragma unroll
    for (int s = 128; s > 0; s >>= 1) {
        if (t < s) sm[t] += sm[t + s];
        __syncthreads();
    }
    if (t == 0) bsum[blockIdx.x] = sm[0];
}

// Phase 2: single-block exclusive scan of NB (<=256) partials; writes off[N]=total
__global__ __launch_bounds__(256) void scan_partials_k(
    int* __restrict__ bsum, int NB, int* __restrict__ off, int N)
{
    __shared__ int ls[256];
    const int t = threadIdx.x;
    int v = (t < NB) ? bsum[t] : 0;
    ls[t] = v;
    __syncthreads();
    #pragma unroll
    for (int d = 1; d < 256; d <<= 1) {
        int u = (t >= d) ? ls[t - d] : 0;
        __syncthreads();
        ls[t] += u;
        __syncthreads();
    }
    if (t < NB) bsum[t] = ls[t] - v;   // exclusive prefix of block sums
    if (t == 255) off[N] = ls[255];    // grand total
}

// Phase 3: per-block local scan + block offset; writes off[] and cur[]
__global__ __launch_bounds__(256) void scan_apply_k(
    const int* __restrict__ cnt, const int* __restrict__ bsum,
    int* __restrict__ off, int* __restrict__ cur, int N)
{
    __shared__ int buf[1024];
    __shared__ int ts[256];
    const int t = threadIdx.x;
    const int base = blockIdx.x * 1024;
    #pragma unroll
    for (int i = 0; i < 4; ++i) {
        int g = base + t + i * 256;
        buf[t + i * 256] = (g < N) ? cnt[g] : 0;
    }
    __syncthreads();
    const int a = buf[t * 4], b = buf[t * 4 + 1], c = buf[t * 4 + 2], d = buf[t * 4 + 3];
    const int s = a + b + c + d;
    ts[t] = s;
    __syncthreads();
    #pragma unroll
    for (int dd = 1; dd < 256; dd <<= 1) {
        int u = (t >= dd) ? ts[t - dd] : 0;
        __syncthreads();
        ts[t] += u;
        __syncthreads();
    }
    const int pre = bsum[blockIdx.x] + ts[t] - s;  // exclusive prefix for elem t*4
    const int o0 = pre, o1 = pre + a, o2 = o1 + b, o3 = o2 + c;
    const int g0 = base + t * 4;
    if (g0 + 3 < N) {
        *reinterpret_cast<int4*>(off + g0) = make_int4(o0, o1, o2, o3);
        *reinterpret_cast<int4*>(cur + g0) = make_int4(o0, o1, o2, o3);
    } else {
        if (g0     < N) { off[g0]     = o0; cur[g0]     = o0; }
        if (g0 + 1 < N) { off[g0 + 1] = o1; cur[g0 + 1] = o1; }
        if (g0 + 2 < N) { off[g0 + 2] = o2; cur[g0 + 2] = o2; }
    }
}

// sorted[pos] = src | (rel << 20), pos = cur[dst]++
__global__ __launch_bounds__(256) void fill_k(
    const int* __restrict__ src, const int* __restrict__ dst,
    const int* __restrict__ rel, int* __restrict__ cur,
    int* __restrict__ sorted, int M)
{
    int i = blockIdx.x * blockDim.x + threadIdx.x;
    if (i >= M) return;
    int p = atomicAdd(&cur[dst[i]], 1);
    sorted[p] = src[i] | (rel[i] << 20);
}

// ---------------------------------------------------------------------------
// Per-dst mean aggregation: 32 lanes own one row, iterate its CSR segment.
__global__ __launch_bounds__(256) void seg_reduce_k(
    const float* __restrict__ tail, const float* __restrict__ rel_emb,
    const int* __restrict__ off, const int* __restrict__ sorted,
    float* __restrict__ aggout, int N)
{
    long long gid = (long long)blockIdx.x * blockDim.x + threadIdx.x;
    int row = (int)(gid >> 5);
    int l = (int)(gid & 31) * 4;
    if (row >= N) return;
    int s = off[row], e = off[row + 1];
    float4 acc = make_float4(0.f, 0.f, 0.f, 0.f);
    int j = s;
    for (; j + 1 < e; j += 2) {
        int p0 = sorted[j], p1 = sorted[j + 1];
        float4 t0 = ld4(tail + (long long)(p0 & 0xFFFFF) * 128 + l);
        float4 r0 = ld4(rel_emb + (long long)(p0 >> 20) * 128 + l);
        float4 t1 = ld4(tail + (long long)(p1 & 0xFFFFF) * 128 + l);
        float4 r1 = ld4(rel_emb + (long long)(p1 >> 20) * 128 + l);
        acc.x = fmaf(t0.x, r0.x, acc.x); acc.y = fmaf(t0.y, r0.y, acc.y);
        acc.z = fmaf(t0.z, r0.z, acc.z); acc.w = fmaf(t0.w, r0.w, acc.w);
        acc.x = fmaf(t1.x, r1.x, acc.x); acc.y = fmaf(t1.y, r1.y, acc.y);
        acc.z = fmaf(t1.z, r1.z, acc.z); acc.w = fmaf(t1.w, r1.w, acc.w);
    }
    if (j < e) {
        int p0 = sorted[j];
        float4 t0 = ld4(tail + (long long)(p0 & 0xFFFFF) * 128 + l);
        float4 r0 = ld4(rel_emb + (long long)(p0 >> 20) * 128 + l);
        acc.x = fmaf(t0.x, r0.x, acc.x); acc.y = fmaf(t0.y, r0.y, acc.y);
        acc.z = fmaf(t0.z, r0.z, acc.z); acc.w = fmaf(t0.w, r0.w, acc.w);
    }
    float sc = 1.0f / (float)max(e - s, 1);
    acc.x *= sc; acc.y *= sc; acc.z *= sc; acc.w *= sc;
    st4(aggout + (long long)row * 128 + l, acc);
}

// ---------------------------------------------------------------------------
// Single-input GEMM (used for unreachable): Out = act(X[idx]@W + b)
template<bool GATHER, bool ACCUM, bool BIAS, bool ACT>
__global__ __launch_bounds__(256) void gemm_rows_k(
    const float* __restrict__ X, const int* __restrict__ idx,
    const float* __restrict__ W, const float* __restrict__ bias,
    float* __restrict__ Out, int N)
{
    __shared__ float XsT[32][128];
    __shared__ float Ws [32][128];
    const int tid = threadIdx.x;
    const int rowbase = blockIdx.x * 128;
    const int r0 = (tid >> 4) * 8;
    const int c0 = (tid & 15) * 8;

    float acc[8][8];
    if (BIAS) {
        #pragma unroll
        for (int j = 0; j < 8; ++j) {
            float bv = bias[c0 + j];
            #pragma unroll
            for (int i = 0; i < 8; ++i) acc[i][j] = bv;
        }
    } else {
        #pragma unroll
        for (int i = 0; i < 8; ++i)
            #pragma unroll
            for (int j = 0; j < 8; ++j) acc[i][j] = 0.0f;
    }

    const int srow = tid >> 3;
    const int skq  = (tid & 7) * 4;
    const int sswz = (tid & 7) << 2;
    const int wkk  = tid >> 5;
    const int wcc  = (tid & 31) * 4;

    for (int k0 = 0; k0 < 128; k0 += 32) {
        __syncthreads();
        #pragma unroll
        for (int p = 0; p < 4; ++p) {
            int row = p * 32 + srow;
            int grow = rowbase + row;
            int cl = grow < N ? grow : (N - 1);
            const float* xr = GATHER ? X + (long long)idx[cl] * 128
                                     : X + (long long)cl * 128;
            float4 v = ld4(xr + k0 + skq);
            int rs = row ^ sswz;
            XsT[skq + 0][rs] = v.x;
            XsT[skq + 1][rs] = v.y;
            XsT[skq + 2][rs] = v.z;
            XsT[skq + 3][rs] = v.w;
        }
        #pragma unroll
        for (int p = 0; p < 4; ++p) {
            int k = p * 8 + wkk;
            st4(&Ws[k][wcc], ld4(W + (long long)(k0 + k) * 128 + wcc));
        }
        __syncthreads();
        #pragma unroll
        for (int k = 0; k < 32; ++k) {
            int A0 = (((r0 >> 2) ^ ((k >> 2) & 7)) << 2);
            float4 x0 = ld4(&XsT[k][A0]);
            float4 x1 = ld4(&XsT[k][A0 ^ 4]);
            float4 w0 = ld4(&Ws[k][c0]);
            float4 w1 = ld4(&Ws[k][c0 + 4]);
            float xs[8] = {x0.x, x0.y, x0.z, x0.w, x1.x, x1.y, x1.z, x1.w};
            float ws[8] = {w0.x, w0.y, w0.z, w0.w, w1.x, w1.y, w1.z, w1.w};
            #pragma unroll
            for (int i = 0; i < 8; ++i)
                #pragma unroll
                for (int j = 0; j < 8; ++j)
                    acc[i][j] = fmaf(xs[i], ws[j], acc[i][j]);
        }
    }

    #pragma unroll
    for (int i = 0; i < 8; ++i) {
        int row = rowbase + r0 + i;
        if (row >= N) continue;
        float* op = Out + (long long)row * 128 + c0;
        float vals[8];
        #pragma unroll
        for (int j = 0; j < 8; ++j) vals[j] = acc[i][j];
        if (ACCUM) {
            float4 o0 = ld4(op), o1 = ld4(op + 4);
            vals[0] += o0.x; vals[1] += o0.y; vals[2] += o0.z; vals[3] += o0.w;
            vals[4] += o1.x; vals[5] += o1.y; vals[6] += o1.z; vals[7] += o1.w;
        }
        if (ACT) {
            #pragma unroll
            for (int j = 0; j < 8; ++j) vals[j] = fast_tanh(vals[j]);
        }
        st4(op,     make_float4(vals[0], vals[1], vals[2], vals[3]));
        st4(op + 4, make_float4(vals[4], vals[5], vals[6], vals[7]));
    }
}

// ---------------------------------------------------------------------------
// Fused dual GEMM: Out = act( X1row@W1 + b + X2row@W2 )
// X1row = X1[idx[row]] if GATHER1 else X1[row]; X2row = X2[row].
// LDS: 4 x 16KB = 64KB/block -> 2 blocks/CU. 8x8 acc per thread, 128 FMA/k.
template<bool GATHER1, bool ACT>
__global__ __launch_bounds__(256) void gemm_fused_k(
    const float* __restrict__ X1, const int* __restrict__ idx,
    const float* __restrict__ X2,
    const float* __restrict__ W1, const float* __restrict__ W2,
    const float* __restrict__ bias, float* __restrict__ Out, int N)
{
    __shared__ float X1sT[32][128];
    __shared__ float X2sT[32][128];
    __shared__ float W1s [32][128];
    __shared__ float W2s [32][128];
    const int tid = threadIdx.x;
    const int rowbase = blockIdx.x * 128;
    const int r0 = (tid >> 4) * 8;
    const int c0 = (tid & 15) * 8;

    float acc[8][8];
    #pragma unroll
    for (int j = 0; j < 8; ++j) {
        float bv = bias[c0 + j];
        #pragma unroll
        for (int i = 0; i < 8; ++i) acc[i][j] = bv;
    }

    const int srow = tid >> 3;
    const int skq  = (tid & 7) * 4;
    const int sswz = (tid & 7) << 2;
    const int wkk  = tid >> 5;
    const int wcc  = (tid & 31) * 4;

    for (int k0 = 0; k0 < 128; k0 += 32) {
        __syncthreads();
        #pragma unroll
        for (int p = 0; p < 4; ++p) {
            int row = p * 32 + srow;
            int grow = rowbase + row;
            int cl = grow < N ? grow : (N - 1);
            const float* x1r = GATHER1 ? X1 + (long long)idx[cl] * 128
                                       : X1 + (long long)cl * 128;
            const float* x2r = X2 + (long long)cl * 128;
            float4 v1 = ld4(x1r + k0 + skq);
            float4 v2 = ld4(x2r + k0 + skq);
            int rs = row ^ sswz;
            X1sT[skq + 0][rs] = v1.x; X1sT[skq + 1][rs] = v1.y;
            X1sT[skq + 2][rs] = v1.z; X1sT[skq + 3][rs] = v1.w;
            X2sT[skq + 0][rs] = v2.x; X2sT[skq + 1][rs] = v2.y;
            X2sT[skq + 2][rs] = v2.z; X2sT[skq + 3][rs] = v2.w;
        }
        #pragma unroll
        for (int p = 0; p < 4; ++p) {
            int k = p * 8 + wkk;
            st4(&W1s[k][wcc], ld4(W1 + (long long)(k0 + k) * 128 + wcc));
            st4(&W2s[k][wcc], ld4(W2 + (long long)(k0 + k) * 128 + wcc));
        }
        __syncthreads();
        #pragma unroll
        for (int k = 0; k < 32; ++k) {
            int A0 = (((r0 >> 2) ^ ((k >> 2) & 7)) << 2);
            float4 a0 = ld4(&X1sT[k][A0]);
            float4 a1 = ld4(&X1sT[k][A0 ^ 4]);
            float4 b0 = ld4(&X2sT[k][A0]);
            float4 b1 = ld4(&X2sT[k][A0 ^ 4]);
            float4 u0 = ld4(&W1s[k][c0]);
            float4 u1 = ld4(&W1s[k][c0 + 4]);
            float4 v0 = ld4(&W2s[k][c0]);
            float4 v1 = ld4(&W2s[k][c0 + 4]);
            float x1s[8] = {a0.x, a0.y, a0.z, a0.w, a1.x, a1.y, a1.z, a1.w};
            float x2s[8] = {b0.x, b0.y, b0.z, b0.w, b1.x, b1.y, b1.z, b1.w};
            float w1s[8] = {u0.x, u0.y, u0.z, u0.w, u1.x, u1.y, u1.z, u1.w};
            float w2s[8] = {v0.x, v0.y, v0.z, v0.w, v1.x, v1.y, v1.z, v1.w};
            #pragma unroll
            for (int i = 0; i < 8; ++i)
                #pragma unroll
                for (int j = 0; j < 8; ++j) {
                    acc[i][j] = fmaf(x1s[i], w1s[j], acc[i][j]);
                    acc[i][j] = fmaf(x2s[i], w2s[j], acc[i][j]);
                }
        }
    }

    #pragma unroll
    for (int i = 0; i < 8; ++i) {
        int row = rowbase + r0 + i;
        if (row >= N) continue;
        float* op = Out + (long long)row * 128 + c0;
        float vals[8];
        #pragma unroll
        for (int j = 0; j < 8; ++j) vals[j] = acc[i][j];
        if (ACT) {
            #pragma unroll
            for (int j = 0; j < 8; ++j) vals[j] = fast_tanh(vals[j]);
        }
        st4(op,     make_float4(vals[0], vals[1], vals[2], vals[3]));
        st4(op + 4, make_float4(vals[4], vals[5], vals[6], vals[7]));
    }
}

// ---------------------------------------------------------------------------
extern "C" void kernel_launch(void* const* d_in, const int* in_sizes, int n_in,
                              void* d_out, int out_size, void* d_ws, size_t ws_size,
                              hipStream_t stream)
{
    const float* ent_emb  = (const float*)d_in[0];
    const float* user_emb = (const float*)d_in[1];
    const float* rel_emb  = (const float*)d_in[2];
    const float* W_self   = (const float*)d_in[3];
    const float* W_nei    = (const float*)d_in[4];
    const float* bvec     = (const float*)d_in[5];
    const int* final_indices = (const int*)d_in[6];
    const int* ent_now1   = (const int*)d_in[7];
    const int* e1_src     = (const int*)d_in[8];
    const int* e1_dst     = (const int*)d_in[9];
    const int* e1_rel     = (const int*)d_in[10];
    const int* e0_src     = (const int*)d_in[11];
    const int* e0_dst     = (const int*)d_in[12];
    const int* e0_rel     = (const int*)d_in[13];
    const int* unreach_idx = (const int*)d_in[14];
    const int* order      = (const int*)d_in[15];

    float* out = (float*)d_out;
    float* ws  = (float*)d_ws;

    // ws layout (floats, then ints; int4 stores need 16B-aligned bases —
    // off1 padded to N1_+4 so off0 stays aligned):
    float* concat = ws;
    float* agg1 = concat + (size_t)E_ * 128;
    float* agg0 = agg1 + (size_t)N1_ * 128;
    int* cur1 = (int*)(agg0 + (size_t)U_ * 128);
    int* cur0 = cur1 + N1_;
    int* off1 = cur0 + U_;
    int* off0 = off1 + (N1_ + 4);
    int* bsum1 = off0 + (U_ + 4);
    int* bsum0 = bsum1 + 256;
    int* sorted1 = bsum0 + 256;
    int* sorted0 = sorted1 + M1_;

    float* h1   = concat;
    float* h2   = concat + (size_t)N1_ * 128;
    float* unre = concat + (size_t)(N1_ + N2_) * 128;

    const int NB1 = (N1_ + 1023) / 1024;   // 79
    const int NB0 = (U_  + 1023) / 1024;   // 49

    // zero histogram counters (cur1|cur0 contiguous)
    hipMemsetAsync(cur1, 0, (size_t)(N1_ + U_) * sizeof(int), stream);

    // h2 = ent_emb[final_indices]
    gather_rows_k<<<(N2_ * 32 + 255) / 256, 256, 0, stream>>>(
        ent_emb, final_indices, h2, N2_);

    // --- layer-1 CSR build + mean-aggregate into agg1 ---
    hist_k<<<(M1_ + 255) / 256, 256, 0, stream>>>(e1_dst, cur1, M1_);
    partial_sums_k<<<NB1, 256, 0, stream>>>(cur1, bsum1, N1_);
    scan_partials_k<<<1, 256, 0, stream>>>(bsum1, NB1, off1, N1_);
    scan_apply_k<<<NB1, 256, 0, stream>>>(cur1, bsum1, off1, cur1, N1_);
    fill_k<<<(M1_ + 255) / 256, 256, 0, stream>>>(
        e1_src, e1_dst, e1_rel, cur1, sorted1, M1_);
    seg_reduce_k<<<(N1_ * 32 + 255) / 256, 256, 0, stream>>>(
        h2, rel_emb, off1, sorted1, agg1, N1_);

    // h1 = tanh( ent_emb[ent_now1]@W_self + b + agg1@W_nei )  (fused)
    gemm_fused_k<true, true><<<(N1_ + 127) / 128, 256, 0, stream>>>(
        ent_emb, ent_now1, agg1, W_self, W_nei, bvec, h1, N1_);

    // --- layer-0 CSR build + mean-aggregate into agg0 ---
    hist_k<<<(M0_ + 255) / 256, 256, 0, stream>>>(e0_dst, cur0, M0_);
    partial_sums_k<<<NB0, 256, 0, stream>>>(cur0, bsum0, U_);
    scan_partials_k<<<1, 256, 0, stream>>>(bsum0, NB0, off0, U_);
    scan_apply_k<<<NB0, 256, 0, stream>>>(cur0, bsum0, off0, cur0, U_);
    fill_k<<<(M0_ + 255) / 256, 256, 0, stream>>>(
        e0_src, e0_dst, e0_rel, cur0, sorted0, M0_);
    seg_reduce_k<<<(U_ * 32 + 255) / 256, 256, 0, stream>>>(
        h1, rel_emb, off0, sorted0, agg0, U_);

    // user_rep = user_emb@W_self + b + agg0@W_nei   (no tanh, fused)
    gemm_fused_k<false, false><<<(U_ + 127) / 128, 256, 0, stream>>>(
        user_emb, nullptr, agg0, W_self, W_nei, bvec, out, U_);

    // unreachable = tanh( ent_emb[unreach_idx]@W_self + b )
    gemm_rows_k<true, false, true, true><<<(NU_ + 127) / 128, 256, 0, stream>>>(
        ent_emb, unreach_idx, W_self, bvec, unre, NU_);

    // final reorder: out[U + i] = concat[order[i]]
    gather_rows_k<<<(E_ * 32 + 255) / 256, 256, 0, stream>>>(
        concat, order, out + (size_t)U_ * 128, E_);
}